// Round 1
// baseline (289.664 us; speedup 1.0000x reference)
//
#include <hip/hip_runtime.h>
#include <stdint.h>

typedef __attribute__((ext_vector_type(8))) short short8;
typedef __attribute__((ext_vector_type(4))) float float4v;

#define HW   4096
#define CC   256
#define SEQQ 32
#define BSZ  32
#define ROWS 64

// Tiled ctx layout (per batch): [s>>2][c>>4][s&3][c&15] shorts.
// s-group = 16 c-tiles x 64 = 1024 shorts, padded to 1032 (bank de-phase).
// Serves BOTH phases from one buffer:
//   phase1 B-frag: 8 contiguous shorts (b128, 2-way banks = free)
//   phase2 B-frag: 8 x ds_read_u16 at immediate offsets (conflict-free)
#define SGRP     1032
#define CTXT_SZ  (8 * SGRP)          // 8256 shorts per batch
#define PSTR_P   40                  // pL row stride (stride-20-dword: 2-way, free)

static __device__ __forceinline__ uint16_t f2bf(float f) {
  union { float f; uint32_t u; } v; v.f = f;
  uint32_t r = v.u + 0x7FFFu + ((v.u >> 16) & 1u);
  return (uint16_t)(r >> 16);
}
static __device__ __forceinline__ float bf2f(uint16_t h) {
  union { uint32_t u; float f; } v; v.u = ((uint32_t)h) << 16;
  return v.f;
}

// ---------------------------------------------------------------------------
// Prep: ctx = context @ W (fp32 accum), split to bf16 hi/lo in TILED layout,
// plus mask -> 32-word bitmask (with storage-format autodetection).
// grid: 257 blocks x 256 threads. Blocks 0..255: 4 rows each; block 256: mask.
// ---------------------------------------------------------------------------
extern "C" __global__ __launch_bounds__(256) void prep_kernel(
    const float* __restrict__ ctx_in,   // [32][32][256]
    const float* __restrict__ Wp,       // [256][256]
    const void*  __restrict__ mask,     // [32][32] unknown storage
    uint32_t* __restrict__ maskbits_ws, // [32] bitmask words
    uint16_t* __restrict__ hiT_ws,      // [32][8256] tiled bf16 hi
    uint16_t* __restrict__ loT_ws)      // [32][8256] tiled bf16 lo
{
  const int t = threadIdx.x;
  if (blockIdx.x == 256) {
    // --- mask storage detection + bitmask ---
    __shared__ int byteFlag;
    if (t == 0) byteFlag = 0;
    __syncthreads();
    const uint8_t* mb = (const uint8_t*)mask;
    int nz = 0;
    for (int i = t; i < 1024; i += 256)
      if ((i & 3) == 1 && mb[i] != 0) nz = 1;
    if (nz) atomicOr(&byteFlag, 1);
    __syncthreads();
    const bool byteMode = (byteFlag != 0);
    const uint32_t* mw32 = (const uint32_t*)mask;
    if (t < 32) {
      uint32_t bits = 0;
      for (int s = 0; s < 32; ++s) {
        bool m = byteMode ? (mb[t * 32 + s] != 0) : (mw32[t * 32 + s] != 0);
        if (m) bits |= (1u << s);
      }
      maskbits_ws[t] = bits;
    }
    return;
  }

  // --- projection: 4 rows of [1024][256]; thread = (row j, 4 channels) ---
  const int r0 = blockIdx.x * 4;
  __shared__ float crow[4][CC];
  for (int i = t; i < 1024; i += 256)
    crow[i >> 8][i & 255] = ctx_in[(size_t)r0 * CC + i];
  __syncthreads();

  const int j  = t >> 6;            // row within block (wave-uniform)
  const int c4 = (t & 63) << 2;     // 4 channels per thread -> float4 W loads
  float4v acc = {0.f, 0.f, 0.f, 0.f};
  #pragma unroll 8
  for (int d = 0; d < CC; ++d) {
    float s = crow[j][d];
    const float4 wv = *(const float4*)&Wp[(size_t)d * CC + c4];
    acc[0] += s * wv.x; acc[1] += s * wv.y;
    acc[2] += s * wv.z; acc[3] += s * wv.w;
  }

  const int row = r0 + j, bb = row >> 5, ss = row & 31;
  const size_t base = (size_t)bb * CTXT_SZ + (ss >> 2) * SGRP + (ss & 3) * 16;
  #pragma unroll
  for (int q = 0; q < 4; ++q) {
    const int c = c4 + q;
    const float v = acc[q];
    const uint16_t h  = f2bf(v);
    const uint16_t lo = f2bf(v - bf2f(h));
    const size_t idx = base + (c >> 4) * 64 + (c & 15);
    hiT_ws[idx] = h;
    loT_ws[idx] = lo;
  }
}

// ---------------------------------------------------------------------------
// Main fused kernel: block = (batch b, 64 spatial rows), 4 waves x 16 rows.
// LDS 38.3 KB -> 4 blocks/CU (was 68.6 KB -> 2). Single barrier (staging);
// pL is same-wave-only so no mid-kernel barrier -> waves fully independent.
// ---------------------------------------------------------------------------
extern "C" __global__ __launch_bounds__(256, 4) void attn_main(
    const float* __restrict__ x,        // [32][4096][256]
    const uint8_t* __restrict__ ws,
    float* __restrict__ out0,           // weighted_context [32][4096][256]
    float* __restrict__ out1)           // word_attn        [32][4096][32]
{
  const uint32_t* maskbits_ws = (const uint32_t*)ws;
  const uint16_t* hiT_ws = (const uint16_t*)(ws + 128);
  const uint16_t* loT_ws = hiT_ws + (size_t)BSZ * CTXT_SZ;

  __shared__ __align__(16) uint16_t hiT[CTXT_SZ];   // 16512 B
  __shared__ __align__(16) uint16_t loT[CTXT_SZ];   // 16512 B
  __shared__ __align__(16) uint16_t pL[ROWS * PSTR_P]; // 5120 B
  __shared__ uint32_t maskW[32];                    // 128 B

  const int tid = threadIdx.x;
  const int b   = blockIdx.y;
  const int n0  = blockIdx.x * ROWS;

  // ---- stage tiled ctx (linear copy; layout pre-built by prep) + mask ----
  {
    const uint4* sHi = (const uint4*)(hiT_ws + (size_t)b * CTXT_SZ);
    const uint4* sLo = (const uint4*)(loT_ws + (size_t)b * CTXT_SZ);
    uint4* dHi = (uint4*)hiT;
    uint4* dLo = (uint4*)loT;
    #pragma unroll
    for (int k = 0; k < 4; ++k) {      // 4*256 = 1024 of 1032 uint4
      dHi[tid + k * 256] = sHi[tid + k * 256];
      dLo[tid + k * 256] = sLo[tid + k * 256];
    }
    if (tid < 8) { dHi[1024 + tid] = sHi[1024 + tid]; dLo[1024 + tid] = sLo[1024 + tid]; }
    if (tid < 32) maskW[tid] = maskbits_ws[tid];
  }
  __syncthreads();

  const int w    = tid >> 6;
  const int lane = tid & 63;
  const int l15  = lane & 15;
  const int quad = lane >> 4;
  const int nbase = n0 + w * 16;

  // ---- phase 1: logits via split-bf16 MFMA (truncation split: exact residual) ----
  float4v acc0 = {0.f, 0.f, 0.f, 0.f};
  float4v acc1 = {0.f, 0.f, 0.f, 0.f};
  const float* xrow = x + ((size_t)b * HW + nbase + l15) * CC + quad * 8;
  // tiled addr of ctx[s=l15][c = k0*32 + quad*8 ...]:
  const int sbase = (l15 >> 2) * SGRP + (l15 & 3) * 16 + (quad >> 1) * 64 + (quad & 1) * 8;

  for (int k0 = 0; k0 < 8; ++k0) {
    float4 xa = *(const float4*)(xrow + k0 * 32);
    float4 xb = *(const float4*)(xrow + k0 * 32 + 4);
    float xv[8] = {xa.x, xa.y, xa.z, xa.w, xb.x, xb.y, xb.z, xb.w};
    short8 ah, al;
    #pragma unroll
    for (int jj = 0; jj < 8; ++jj) {
      uint32_t u = __float_as_uint(xv[jj]);
      ah[jj] = (short)(u >> 16);                              // trunc hi
      float r = xv[jj] - __uint_as_float(u & 0xFFFF0000u);    // exact residual
      al[jj] = (short)(__float_as_uint(r) >> 16);             // trunc lo
    }
    const int ka = sbase + k0 * 128;
    short8 bh0 = *(const short8*)&hiT[ka];
    short8 bl0 = *(const short8*)&loT[ka];
    short8 bh1 = *(const short8*)&hiT[ka + 4 * SGRP];
    short8 bl1 = *(const short8*)&loT[ka + 4 * SGRP];
    acc0 = __builtin_amdgcn_mfma_f32_16x16x32_bf16(ah, bh0, acc0, 0, 0, 0);
    acc0 = __builtin_amdgcn_mfma_f32_16x16x32_bf16(ah, bl0, acc0, 0, 0, 0);
    acc0 = __builtin_amdgcn_mfma_f32_16x16x32_bf16(al, bh0, acc0, 0, 0, 0);
    acc1 = __builtin_amdgcn_mfma_f32_16x16x32_bf16(ah, bh1, acc1, 0, 0, 0);
    acc1 = __builtin_amdgcn_mfma_f32_16x16x32_bf16(ah, bl1, acc1, 0, 0, 0);
    acc1 = __builtin_amdgcn_mfma_f32_16x16x32_bf16(al, bh1, acc1, 0, 0, 0);
  }

  // ---- softmax over 32 logits per row (mask row = n & 31 quirk) ----
  #pragma unroll
  for (int r = 0; r < 4; ++r) {
    const int n = nbase + quad * 4 + r;
    const uint32_t mwd = maskW[n & 31];
    float v0 = (mwd & (1u << l15))        ? -1e30f : acc0[r];
    float v1 = (mwd & (1u << (l15 + 16))) ? -1e30f : acc1[r];
    float mx = fmaxf(v0, v1);
    #pragma unroll
    for (int off = 1; off < 16; off <<= 1)
      mx = fmaxf(mx, __shfl_xor(mx, off, 64));
    float e0 = __expf(v0 - mx);
    float e1 = __expf(v1 - mx);
    float sm = e0 + e1;
    #pragma unroll
    for (int off = 1; off < 16; off <<= 1)
      sm += __shfl_xor(sm, off, 64);
    float inv = 1.0f / sm;
    float p0 = e0 * inv, p1 = e1 * inv;
    size_t o1 = ((size_t)b * HW + n) * SEQQ;
    out1[o1 + l15]      = p0;
    out1[o1 + 16 + l15] = p1;
    pL[(w * 16 + quad * 4 + r) * PSTR_P + l15]      = f2bf(p0);
    pL[(w * 16 + quad * 4 + r) * PSTR_P + 16 + l15] = f2bf(p1);
  }
  // NO barrier: pL rows [w*16 .. w*16+15] are written and read by the SAME
  // wave; compiler-inserted lgkmcnt orders the within-wave LDS RAW.

  // ---- phase 2: O = P * ctx; B-frag gathered from tiled hiT via u16 reads
  //      (one base VGPR + immediate offsets; 2 lanes/dword -> conflict-free) ----
  short8 pa = *(const short8*)&pL[(w * 16 + l15) * PSTR_P + quad * 8];
  const int cbase = quad * 2 * SGRP + l15;   // shorts
  #pragma unroll
  for (int ct = 0; ct < 16; ++ct) {
    short8 bfr;
    #pragma unroll
    for (int jj = 0; jj < 8; ++jj)
      bfr[jj] = (short)hiT[cbase + (jj >> 2) * SGRP + ct * 64 + (jj & 3) * 16];
    float4v z = {0.f, 0.f, 0.f, 0.f};
    float4v d = __builtin_amdgcn_mfma_f32_16x16x32_bf16(pa, bfr, z, 0, 0, 0);
    #pragma unroll
    for (int r = 0; r < 4; ++r) {
      size_t o0 = ((size_t)b * HW + nbase + quad * 4 + r) * CC + ct * 16 + l15;
      out0[o0] = d[r];
    }
  }
}

// ---------------------------------------------------------------------------
extern "C" void kernel_launch(void* const* d_in, const int* in_sizes, int n_in,
                              void* d_out, int out_size, void* d_ws, size_t ws_size,
                              hipStream_t stream) {
  const float* x      = (const float*)d_in[0];
  // d_in[1] = sentence (unused by reference call())
  const float* ctx_in = (const float*)d_in[2];
  const void*  mask   = d_in[3];
  const float* Wp     = (const float*)d_in[4];

  float* out0 = (float*)d_out;                       // [32][4096][256]
  float* out1 = out0 + (size_t)BSZ * HW * CC;        // [32][4096][32]

  uint8_t*  ws          = (uint8_t*)d_ws;
  uint32_t* maskbits_ws = (uint32_t*)ws;                         // 128 B
  uint16_t* hiT_ws      = (uint16_t*)(ws + 128);                 // 528384 B
  uint16_t* loT_ws      = hiT_ws + (size_t)BSZ * CTXT_SZ;        // 528384 B

  prep_kernel<<<257, 256, 0, stream>>>(ctx_in, Wp, mask, maskbits_ws,
                                       hiT_ws, loT_ws);
  attn_main<<<dim3(HW / ROWS, BSZ), 256, 0, stream>>>(x, ws, out0, out1);
}